// Round 19
// baseline (775.633 us; speedup 1.0000x reference)
//
#include <hip/hip_runtime.h>
#include <hip/hip_bf16.h>
#include <math.h>
#include <stdint.h>

#define NEGF (-1e30f)
#define LOG2E 1.44269504088896340736f
#define LN2 0.69314718055994530942f

// lp row layout for the CTC scan: 64 lane-groups x 8 bf16 (5 used, 3 pad)
#define LPROW 512

typedef short bf16x8 __attribute__((ext_vector_type(8)));
typedef float f32x4 __attribute__((ext_vector_type(4)));

__device__ __forceinline__ unsigned short f2b(float x) {
  __hip_bfloat16 h = __float2bfloat16(x);
  return *reinterpret_cast<unsigned short*>(&h);
}
__device__ __forceinline__ float b2f(unsigned short u) {
  __hip_bfloat16 h;
  *reinterpret_cast<unsigned short*>(&h) = u;
  return __bfloat162float(h);
}
__device__ __forceinline__ float gelu_exact(float x) {
  return 0.5f * x * (1.0f + erff(x * 0.70710678118654752440f));
}

#if __has_builtin(__builtin_amdgcn_logf)
__device__ __forceinline__ float fast_log2(float x) { return __builtin_amdgcn_logf(x); }
#else
__device__ __forceinline__ float fast_log2(float x) { return log2f(x); }
#endif

// VALU-speed cross-lane helpers (no LDS/ds_bpermute on the critical path)
template<int CTRL>
__device__ __forceinline__ float dpp_shr(float x) {
  // row_shr:N within 16-lane rows; bound_ctrl=1 -> out-of-row reads give 0
  return __int_as_float(__builtin_amdgcn_update_dpp(
      0, __float_as_int(x), 0x110 | CTRL, 0xf, 0xf, true));
}
__device__ __forceinline__ float readlane_f(float x, int l) {
  return __int_as_float(__builtin_amdgcn_readlane(__float_as_int(x), l));
}

// inline-asm SINGLE-DWORD global load: one "=v"(uint) output — the trivially
// register-allocatable asm case (no struct/tuple lowering path). Issue point
// pinned by asm volatile; result valid after matching s_waitcnt vmcnt(N).
template<int OFF>
__device__ __forceinline__ unsigned int gload_d(const void* p) {
  unsigned int r;
  if constexpr (OFF == 0) {
    asm volatile("global_load_dword %0, %1, off" : "=v"(r) : "v"(p));
  } else if constexpr (OFF == 4) {
    asm volatile("global_load_dword %0, %1, off offset:4" : "=v"(r) : "v"(p));
  } else {
    asm volatile("global_load_dword %0, %1, off offset:8" : "=v"(r) : "v"(p));
  }
  return r;
}

// async global->LDS, 16B per lane (GEMM staging).
__device__ __forceinline__ void gload16(void* lds, const void* g) {
  __builtin_amdgcn_global_load_lds(
      (__attribute__((address_space(1))) void*)(uintptr_t)g,
      (__attribute__((address_space(3))) void*)(unsigned int)(uintptr_t)lds,
      16, 0, 0);
}

// ---------------------------------------------------------------------------
// fp32 -> bf16 elementwise
// ---------------------------------------------------------------------------
__global__ __launch_bounds__(256) void cvt_enc_kernel(
    const float* __restrict__ in, unsigned short* __restrict__ out, long n4)
{
  long i = (long)blockIdx.x * blockDim.x + threadIdx.x;
  const long stride = (long)gridDim.x * blockDim.x;
  for (; i < n4; i += stride) {
    float4 v = ((const float4*)in)[i];
    ushort4 o;
    o.x = f2b(v.x); o.y = f2b(v.y); o.z = f2b(v.z); o.w = f2b(v.w);
    ((ushort4*)out)[i] = o;
  }
}

// ---------------------------------------------------------------------------
// W (K,N) fp32 -> WT (N,K) bf16, 32x32 LDS tile transpose
// ---------------------------------------------------------------------------
__global__ __launch_bounds__(256) void cvt_wt_kernel(
    const float* __restrict__ W, unsigned short* __restrict__ WT, int K, int N)
{
  __shared__ float tile[32][33];
  const int n0 = blockIdx.x * 32, k0 = blockIdx.y * 32;
  const int tx = threadIdx.x, ty = threadIdx.y;  // 32 x 8
#pragma unroll
  for (int i = 0; i < 32; i += 8) {
    int k = k0 + ty + i, n = n0 + tx;
    tile[ty + i][tx] = (k < K && n < N) ? W[(long)k * N + n] : 0.f;
  }
  __syncthreads();
#pragma unroll
  for (int i = 0; i < 32; i += 8) {
    int n = n0 + ty + i, k = k0 + tx;
    if (n < N && k < K) WT[(long)n * K + k] = f2b(tile[tx][ty + i]);
  }
}

// ---------------------------------------------------------------------------
// m97-structure MFMA GEMM: 128x128 tile, BK=32, 256 threads (4 waves, 2x2).
// 1-D grid + bijective XCD swizzle (T1). nwg % 8 == 0 required.
// ---------------------------------------------------------------------------
template<int NFULL, int EPI>
__global__ __launch_bounds__(256, 2) void gemm128_kernel(
    const unsigned short* __restrict__ A,
    const unsigned short* __restrict__ WT,
    const float* __restrict__ bias,
    unsigned short* __restrict__ out,
    float2* __restrict__ partials,
    int K, int gx, int nwg)
{
  extern __shared__ char smem[];
  unsigned short* As = (unsigned short*)smem;            // 2 bufs x 4096 shorts
  unsigned short* Bs = (unsigned short*)(smem + 16384);  // 2 bufs x 4096 shorts

  const int tid = threadIdx.x, lane = tid & 63, w = tid >> 6;
  const int wr = w >> 1, wc = w & 1;
  const int cl = lane & 15, g = lane >> 4;
  const int bid = blockIdx.x;
  const int wid = (bid & 7) * (nwg >> 3) + (bid >> 3);  // XCD-contiguous chunks
  const int bx = wid % gx;
  const long row0 = (long)(wid / gx) * 128;
  const int col0 = bx * 128;

  const int ch0 = w * 64 + lane;
  const int ch1 = 256 + ch0;
  const unsigned short* Ag0 = A + (row0 + (ch0 >> 2)) * K + (ch0 & 3) * 8;
  const unsigned short* Ag1 = A + (row0 + (ch1 >> 2)) * K + (ch1 & 3) * 8;
  const unsigned short* Bg0 = WT + (long)(col0 + (ch0 >> 2)) * K + (ch0 & 3) * 8;
  const unsigned short* Bg1 = WT + (long)(col0 + (ch1 >> 2)) * K + (ch1 & 3) * 8;
  unsigned short* Al0 = As + w * 512;
  unsigned short* Al1 = As + 2048 + w * 512;
  unsigned short* Bl0 = Bs + w * 512;
  unsigned short* Bl1 = Bs + 2048 + w * 512;

#define STAGE(buf, kt)                          \
  do {                                          \
    const int _ko = (kt) * 32;                  \
    gload16(Al0 + (buf) * 4096, Ag0 + _ko);     \
    gload16(Al1 + (buf) * 4096, Ag1 + _ko);     \
    gload16(Bl0 + (buf) * 4096, Bg0 + _ko);     \
    gload16(Bl1 + (buf) * 4096, Bg1 + _ko);     \
  } while (0)

  f32x4 acc[4][4];
#pragma unroll
  for (int mt = 0; mt < 4; ++mt)
#pragma unroll
    for (int nt = 0; nt < 4; ++nt) acc[mt][nt] = (f32x4){0.f, 0.f, 0.f, 0.f};

  const int NKT = K / 32;
  STAGE(0, 0);
  __syncthreads();
  int buf = 0;
  for (int kt = 0; kt < NKT; ++kt) {
    if (kt + 1 < NKT) STAGE(buf ^ 1, kt + 1);
    const unsigned short* Ab = As + buf * 4096;
    const unsigned short* Bb = Bs + buf * 4096;
    bf16x8 af[4], bfr[4];
#pragma unroll
    for (int mt = 0; mt < 4; ++mt)
      af[mt] = *(const bf16x8*)&Ab[(((wr * 64 + mt * 16 + cl) << 2) + g) * 8];
#pragma unroll
    for (int nt = 0; nt < 4; ++nt)
      bfr[nt] = *(const bf16x8*)&Bb[(((wc * 64 + nt * 16 + cl) << 2) + g) * 8];
#pragma unroll
    for (int mt = 0; mt < 4; ++mt)
#pragma unroll
      for (int nt = 0; nt < 4; ++nt)
        acc[mt][nt] = __builtin_amdgcn_mfma_f32_16x16x32_bf16(
            af[mt], bfr[nt], acc[mt][nt], 0, 0, 0);
    __syncthreads();
    buf ^= 1;
  }
#undef STAGE

  float bv[4];
#pragma unroll
  for (int nt = 0; nt < 4; ++nt) bv[nt] = bias[col0 + wc * 64 + nt * 16 + cl];
#pragma unroll
  for (int mt = 0; mt < 4; ++mt)
#pragma unroll
    for (int nt = 0; nt < 4; ++nt)
#pragma unroll
      for (int j = 0; j < 4; ++j) {
        float v = acc[mt][nt][j] + bv[nt];
        if (EPI == 1) v = gelu_exact(v);
        acc[mt][nt][j] = v;
      }

  if (EPI == 2) {
#pragma unroll
    for (int mt = 0; mt < 4; ++mt)
#pragma unroll
      for (int j = 0; j < 4; ++j) {
        float mx = fmaxf(fmaxf(acc[mt][0][j], acc[mt][1][j]),
                         fmaxf(acc[mt][2][j], acc[mt][3][j]));
#pragma unroll
        for (int off = 1; off < 16; off <<= 1)
          mx = fmaxf(mx, __shfl_xor(mx, off));
        float sm = 0.f;
#pragma unroll
        for (int nt = 0; nt < 4; ++nt) sm += expf(acc[mt][nt][j] - mx);
#pragma unroll
        for (int off = 1; off < 16; off <<= 1) sm += __shfl_xor(sm, off);
        if (cl == 0) {
          long m = row0 + wr * 64 + mt * 16 + g * 4 + j;
          partials[m * 16 + bx * 2 + wc] = make_float2(mx, sm);
        }
      }
  }

  unsigned short* Ct = (unsigned short*)smem;  // [128][136]
#pragma unroll
  for (int mt = 0; mt < 4; ++mt)
#pragma unroll
    for (int nt = 0; nt < 4; ++nt)
#pragma unroll
      for (int j = 0; j < 4; ++j)
        Ct[(wr * 64 + mt * 16 + g * 4 + j) * 136 + wc * 64 + nt * 16 + cl] =
            f2b(acc[mt][nt][j]);
  __syncthreads();
  for (int idx = tid; idx < 2048; idx += 256) {
    int r = idx >> 4, ch = idx & 15;
    *(bf16x8*)&out[(row0 + r) * NFULL + col0 + ch * 8] =
        *(const bf16x8*)&Ct[r * 136 + ch * 8];
  }
}

// ---------------------------------------------------------------------------
// LayerNorm in place on bf16, one wave per row
// ---------------------------------------------------------------------------
template<int D>
__global__ __launch_bounds__(256) void ln_bf16_kernel(
    unsigned short* __restrict__ X, const float* __restrict__ g,
    const float* __restrict__ bt, long M)
{
  constexpr int NI = D / 256;
  const int lane = threadIdx.x & 63;
  const int wid = threadIdx.x >> 6;
  const long row = (long)blockIdx.x * 4 + wid;
  if (row >= M) return;

  float v[NI * 4];
  float s = 0.f;
#pragma unroll
  for (int i = 0; i < NI; ++i) {
    ushort4 u = *(const ushort4*)&X[row * D + (i * 64 + lane) * 4];
    v[i * 4 + 0] = b2f(u.x); v[i * 4 + 1] = b2f(u.y);
    v[i * 4 + 2] = b2f(u.z); v[i * 4 + 3] = b2f(u.w);
    s += v[i * 4 + 0] + v[i * 4 + 1] + v[i * 4 + 2] + v[i * 4 + 3];
  }
#pragma unroll
  for (int off = 32; off; off >>= 1) s += __shfl_xor(s, off);
  const float mu = s * (1.0f / D);
  float q = 0.f;
#pragma unroll
  for (int i = 0; i < NI * 4; ++i) { float d = v[i] - mu; q += d * d; }
#pragma unroll
  for (int off = 32; off; off >>= 1) q += __shfl_xor(q, off);
  const float rs = rsqrtf(q * (1.0f / D) + 1e-6f);
#pragma unroll
  for (int i = 0; i < NI; ++i) {
    ushort4 o;
    int c = (i * 64 + lane) * 4;
    o.x = f2b((v[i * 4 + 0] - mu) * rs * g[c + 0] + bt[c + 0]);
    o.y = f2b((v[i * 4 + 1] - mu) * rs * g[c + 1] + bt[c + 1]);
    o.z = f2b((v[i * 4 + 2] - mu) * rs * g[c + 2] + bt[c + 2]);
    o.w = f2b((v[i * 4 + 3] - mu) * rs * g[c + 3] + bt[c + 3]);
    *(ushort4*)&X[row * D + c] = o;
  }
}

// ---------------------------------------------------------------------------
// logz combine + label gather. Stores LINEAR probabilities scaled by 2^10
// as BF16: p'[s] = exp(score[lab] - logz) * 1024, 0 for pad states (s >= S).
// ---------------------------------------------------------------------------
__global__ __launch_bounds__(256) void logz_gather_kernel(
    const unsigned short* __restrict__ scores,  // (M, 1024) bf16
    const float2* __restrict__ partials,        // (M, 16)
    const int* __restrict__ targets,
    unsigned short* __restrict__ lp_ext,        // (B, T, LPROW) bf16
    long Mtot, int T, int B, int L, int S)
{
  const int w = threadIdx.x >> 6, lane = threadIdx.x & 63;
  const long m = (long)blockIdx.x * 4 + w;
  if (m >= Mtot) return;

  float2 pp = partials[m * 16 + (lane & 15)];
  float Mx = pp.x, Sv = pp.y;
#pragma unroll
  for (int off = 1; off < 16; off <<= 1) {
    float Mo = __shfl_xor(Mx, off);
    float So = __shfl_xor(Sv, off);
    float Mn = fmaxf(Mx, Mo);
    Sv = Sv * expf(Mx - Mn) + So * expf(Mo - Mn);
    Mx = Mn;
  }
  const float logz = Mx + logf(Sv);
  const int b = (int)(m % B);
  const int t = (int)(m / B);
  const unsigned short* srow = scores + m * 1024;
  bf16x8 o = {0, 0, 0, 0, 0, 0, 0, 0};
#pragma unroll
  for (int j = 0; j < 5; ++j) {
    int s = lane * 5 + j;
    if (s < S) {
      int lab = (s & 1) ? targets[b * L + (s >> 1)] : 0;
      o[j] = (short)f2b(expf(b2f(srow[lab]) - logz) * 1024.0f);  // p * 2^10
    }
  }
  *(bf16x8*)&lp_ext[((long)b * T + t) * LPROW + lane * 8] = o;
}

// ---------------------------------------------------------------------------
// CTC forward scan, LINEAR DOMAIN: one WAVE per batch element. 8-row ring of
// SCALAR DWORD registers (24 named uints — single-register asm outputs, the
// one lowering path that cannot hit struct/tuple scratch round-trips). Per
// row: s_waitcnt vmcnt(21) + sched_barrier(0), consume 3 dwords (5 bf16),
// re-issue 3 pinned global_load_dword. Cross-lane via DPP row_shr:1 +
// readlane boundary fix. Exact power-of-2 renorm every 8 rows. No LDS, no
// barriers, no transcendentals in the loop. LP over-allocated for tail.
// ---------------------------------------------------------------------------
__global__ __launch_bounds__(64, 1) void ctc_scan_kernel(
    const unsigned short* __restrict__ pr,  // (B, T, LPROW) bf16: prob * 1024
    const int* __restrict__ targets, const int* __restrict__ inlens,
    const int* __restrict__ tlens, float* __restrict__ partial,
    int T, int B, int L, int S)
{
  const int b = blockIdx.x;
  const int lane = threadIdx.x;
  const int s0 = lane * 5;
  const int inlen = inlens[b];
  const int tlen = tlens[b];
  const int send = 2 * tlen;
  const int capT = inlen - 1;
  const bool is16 = (lane == 16), is32 = (lane == 32), is48 = (lane == 48);

  const unsigned short* lpb = pr + (long)b * T * LPROW + lane * 8;

  float skm[5];  // skip multiplier 0/1
#pragma unroll
  for (int j = 0; j < 5; ++j) {
    int s = s0 + j;
    float sk = 0.f;
    if (s < S && (s & 1) && s >= 3) {
      int lab = targets[b * L + (s >> 1)];
      int lab2 = targets[b * L + (s >> 1) - 1];
      sk = ((lab != 0) && (lab != lab2)) ? 1.f : 0.f;
    }
    skm[j] = sk;
  }

  // init alpha' from row 0 (plain load; pad states hold 0 in LP)
  float a[5];
  float abv = 0.f, alv = 0.f;
  int corr = 0, corr_cap = 0;
#pragma unroll
  for (int j = 0; j < 5; ++j) {
    int s = s0 + j;
    a[j] = (s <= 1) ? b2f(lpb[j]) : 0.f;
  }
  if (capT == 0) {
#pragma unroll
    for (int j = 0; j < 5; ++j) {
      int s = s0 + j;
      if (s == send) abv = a[j];
      if (s == send - 1) alv = a[j];
    }
    corr_cap = corr;
  }

#define CTC_WAIT                                          \
  do {                                                    \
    asm volatile("s_waitcnt vmcnt(21)" ::: "memory");     \
    __builtin_amdgcn_sched_barrier(0);                    \
  } while (0)

  // one DP row from 3 raw dwords holding 5 bf16 (shift/mask -> f32).
#define CTC_PROCESS(dx, dy, dz, tcur)                                         \
  do {                                                                        \
    float p0 = __uint_as_float((dx) << 16);                                   \
    float p1 = __uint_as_float((dx) & 0xffff0000u);                           \
    float p2 = __uint_as_float((dy) << 16);                                   \
    float p3 = __uint_as_float((dy) & 0xffff0000u);                           \
    float p4 = __uint_as_float((dz) << 16);                                   \
    float r15 = readlane_f(a[4], 15), r31 = readlane_f(a[4], 31),             \
          r47 = readlane_f(a[4], 47);                                         \
    float q15 = readlane_f(a[3], 15), q31 = readlane_f(a[3], 31),             \
          q47 = readlane_f(a[3], 47);                                         \
    float o_m1 = dpp_shr<1>(a[4]);                                            \
    float o_m2 = dpp_shr<1>(a[3]);                                            \
    o_m1 = is16 ? r15 : o_m1; o_m1 = is32 ? r31 : o_m1;                       \
    o_m1 = is48 ? r47 : o_m1;                                                 \
    o_m2 = is16 ? q15 : o_m2; o_m2 = is32 ? q31 : o_m2;                       \
    o_m2 = is48 ? q47 : o_m2;                                                 \
    float na0 = fmaf(skm[0], o_m2, a[0] + o_m1) * p0;                         \
    float na1 = fmaf(skm[1], o_m1, a[1] + a[0]) * p1;                         \
    float na2 = fmaf(skm[2], a[0], a[2] + a[1]) * p2;                         \
    float na3 = fmaf(skm[3], a[1], a[3] + a[2]) * p3;                         \
    float na4 = fmaf(skm[4], a[2], a[4] + a[3]) * p4;                         \
    a[0] = na0; a[1] = na1; a[2] = na2; a[3] = na3; a[4] = na4;               \
    if ((tcur) == capT) {                                                     \
      _Pragma("unroll")                                                       \
      for (int j = 0; j < 5; ++j) {                                           \
        int s = s0 + j;                                                       \
        if (s == send) abv = a[j];                                            \
        if (s == send - 1) alv = a[j];                                        \
      }                                                                       \
      corr_cap = corr;                                                        \
    }                                                                         \
  } while (0)

  // exact power-of-2 wave renorm, VALU-only (DPP prefix-max + readlanes)
#define CTC_RENORM                                                            \
  do {                                                                        \
    float m_ = fmaxf(fmaxf(fmaxf(a[0], a[1]), fmaxf(a[2], a[3])), a[4]);      \
    m_ = fmaxf(m_, dpp_shr<1>(m_));                                           \
    m_ = fmaxf(m_, dpp_shr<2>(m_));                                           \
    m_ = fmaxf(m_, dpp_shr<4>(m_));                                           \
    m_ = fmaxf(m_, dpp_shr<8>(m_));                                           \
    float mx = fmaxf(fmaxf(readlane_f(m_, 15), readlane_f(m_, 31)),           \
                     fmaxf(readlane_f(m_, 47), readlane_f(m_, 63)));          \
    int e;                                                                    \
    (void)frexpf(mx, &e);  /* mx == 0 -> e = 0 -> no-op */                    \
    float sc = ldexpf(1.f, -e);                                               \
    _Pragma("unroll")                                                         \
    for (int j = 0; j < 5; ++j) a[j] *= sc;                                   \
    corr += e;                                                                \
  } while (0)

// consume slot (row t), then re-issue its 3 dwords for row t+8
#define CTC_STEP(gx, gy, gz)                                  \
  do {                                                        \
    CTC_WAIT;                                                 \
    if (t < T) CTC_PROCESS(gx, gy, gz, t);                    \
    const void* _ap = lpb + (long)(t + 8) * LPROW;            \
    gx = gload_d<0>(_ap);                                     \
    gy = gload_d<4>(_ap);                                     \
    gz = gload_d<8>(_ap);                                     \
    ++t;                                                      \
  } while (0)

  // prologue: 8 slots x 3 scalar dwords, rows 1..8 (issue order pinned)
  unsigned int g0x, g0y, g0z, g1x, g1y, g1z, g2x, g2y, g2z, g3x, g3y, g3z;
  unsigned int g4x, g4y, g4z, g5x, g5y, g5z, g6x, g6y, g6z, g7x, g7y, g7z;
  {
    const void* p1_ = lpb + (long)1 * LPROW;
    g0x = gload_d<0>(p1_); g0y = gload_d<4>(p1_); g0z = gload_d<8>(p1_);
    const void* p2_ = lpb + (long)2 * LPROW;
    g1x = gload_d<0>(p2_); g1y = gload_d<4>(p2_); g1z = gload_d<8>(p2_);
    const void* p3_ = lpb + (long)3 * LPROW;
    g2x = gload_d<0>(p3_); g2y = gload_d<4>(p3_); g2z = gload_d<8>(p3_);
    const void* p4_ = lpb + (long)4 * LPROW;
    g3x = gload_d<0>(p4_); g3y = gload_d<4>(p4_); g3z = gload_d<8>(p4_);
    const void* p5_ = lpb + (long)5 * LPROW;
    g4x = gload_d<0>(p5_); g4y = gload_d<4>(p5_); g4z = gload_d<8>(p5_);
    const void* p6_ = lpb + (long)6 * LPROW;
    g5x = gload_d<0>(p6_); g5y = gload_d<4>(p6_); g5z = gload_d<8>(p6_);
    const void* p7_ = lpb + (long)7 * LPROW;
    g6x = gload_d<0>(p7_); g6y = gload_d<4>(p7_); g6z = gload_d<8>(p7_);
    const void* p8_ = lpb + (long)8 * LPROW;
    g7x = gload_d<0>(p8_); g7y = gload_d<4>(p8_); g7z = gload_d<8>(p8_);
  }

  const int NCH = (T - 1 + 7) / 8;
  int t = 1;
  for (int c = 0; c < NCH; ++c) {
    CTC_STEP(g0x, g0y, g0z);
    CTC_STEP(g1x, g1y, g1z);
    CTC_STEP(g2x, g2y, g2z);
    CTC_STEP(g3x, g3y, g3z);
    CTC_STEP(g4x, g4y, g4z);
    CTC_STEP(g5x, g5y, g5z);
    CTC_STEP(g6x, g6y, g6z);
    CTC_STEP(g7x, g7y, g7z);
    CTC_RENORM;
  }
  asm volatile("s_waitcnt vmcnt(0)" ::: "memory");

  // reduce the (single-lane-held) captures across the wave (one-time)
#pragma unroll
  for (int off = 32; off; off >>= 1) {
    abv = fmaxf(abv, __shfl_xor(abv, off));
    alv = fmaxf(alv, __shfl_xor(alv, off));
  }
  if (lane == 0) {
    // true log2(alpha) = log2(alpha') + corr_cap - 10*inlen
    float l2 = fast_log2(abv + alv) + (float)corr_cap - 10.0f * (float)inlen;
    float loss = -LN2 * l2;
    if (!(loss <= 1e29f)) loss = 0.f;  // zero_infinity (also catches NaN)
    partial[b] = loss / (float)tlen;
  }
}

__global__ void reduce_kernel(const float* __restrict__ partial,
                              float* __restrict__ out, int B)
{
  int lane = threadIdx.x;
  float v = (lane < B) ? partial[lane] : 0.f;
#pragma unroll
  for (int off = 32; off; off >>= 1) v += __shfl_xor(v, off);
  if (lane == 0) out[0] = v / (float)B;
}

// ---------------------------------------------------------------------------
extern "C" void kernel_launch(void* const* d_in, const int* in_sizes, int n_in,
                              void* d_out, int out_size, void* d_ws, size_t ws_size,
                              hipStream_t stream) {
  const float* enc = (const float*)d_in[0];
  const float* Wp  = (const float*)d_in[1];
  const float* bp  = (const float*)d_in[2];
  const float* Wt  = (const float*)d_in[3];
  const float* btr = (const float*)d_in[4];
  const float* lng = (const float*)d_in[5];
  const float* lnb = (const float*)d_in[6];
  const float* Wd  = (const float*)d_in[7];
  const float* bd  = (const float*)d_in[8];
  const int* tgt   = (const int*)d_in[9];
  const int* inl   = (const int*)d_in[10];
  const int* tll   = (const int*)d_in[11];

  const int D = in_sizes[2];              // 768
  const int V = in_sizes[8];              // 1024
  const int B = in_sizes[10];             // 32
  const int L = in_sizes[9] / B;          // 150
  const long M = (long)in_sizes[0] / D;   // T*B = 64000
  const int T = (int)(M / B);             // 2000
  const int S = 2 * L + 1;                // 301

  char* wsb = (char*)d_ws;
  size_t off = 0;
  auto alloc = [&](size_t bytes) { char* p = wsb + off; off += (bytes + 255) & ~(size_t)255; return p; };
  unsigned short* encb   = (unsigned short*)alloc((size_t)M * D * 2);
  char* x1region         = alloc((size_t)M * V * 2);
  unsigned short* X1b    = (unsigned short*)x1region;   // dead after gemm2
  unsigned short* scores = (unsigned short*)x1region;   // written by gemm3
  unsigned short* X2b    = encb;                        // encb dead after gemm1
  // +64KB slack: ctc tail prefetch reads up to 8 rows past the end
  unsigned short* LP     = (unsigned short*)alloc((size_t)B * T * LPROW * 2 + 65536);
  float2* partials       = (float2*)alloc((size_t)M * 16 * sizeof(float2));
  unsigned short* WpT    = (unsigned short*)alloc((size_t)D * D * 2);
  unsigned short* WtT    = (unsigned short*)alloc((size_t)D * D * 2);
  unsigned short* WdT    = (unsigned short*)alloc((size_t)D * V * 2);
  float* partial         = (float*)alloc(256);

  cvt_wt_kernel<<<dim3(D / 32, D / 32), dim3(32, 8), 0, stream>>>(Wp, WpT, D, D);
  cvt_wt_kernel<<<dim3(D / 32, D / 32), dim3(32, 8), 0, stream>>>(Wt, WtT, D, D);
  cvt_wt_kernel<<<dim3(V / 32, D / 32), dim3(32, 8), 0, stream>>>(Wd, WdT, D, V);
  cvt_enc_kernel<<<2048, 256, 0, stream>>>(enc, encb, (long)M * D / 4);

  const size_t smemg = 34816;
  const int gx12 = D / 128, nwg12 = gx12 * (int)(M / 128);  // 6*500 = 3000
  const int gx3 = V / 128, nwg3 = gx3 * (int)(M / 128);     // 8*500 = 4000

  gemm128_kernel<768, 0><<<nwg12, 256, smemg, stream>>>(
      encb, WpT, bp, X1b, nullptr, D, gx12, nwg12);
  gemm128_kernel<768, 1><<<nwg12, 256, smemg, stream>>>(
      X1b, WtT, btr, X2b, nullptr, D, gx12, nwg12);
  ln_bf16_kernel<768><<<(int)(M / 4), 256, 0, stream>>>(X2b, lng, lnb, M);
  gemm128_kernel<1024, 2><<<nwg3, 256, smemg, stream>>>(
      X2b, WdT, bd, scores, partials, D, gx3, nwg3);

  logz_gather_kernel<<<(int)(M / 4), 256, 0, stream>>>(
      scores, partials, tgt, LP, M, T, B, L, S);
  ctc_scan_kernel<<<B, 64, 0, stream>>>(LP, tgt, inl, tll, partial, T, B, L, S);
  reduce_kernel<<<1, 64, 0, stream>>>(partial, (float*)d_out, B);
}